// Round 11
// baseline (44.290 us; speedup 1.0000x reference)
//
#include <hip/hip_runtime.h>

// DQSN forward, fully fused (v8): R10 structure + dual h-streams per
// iteration (2x ILP) + register headroom for load pipelining.
//
// out[b,o] = sum_h W2[o,h] * A[b,h] + b2[o] * (1 - 2^-16)
// A depends only on n = first j in 1..16 with fp32-cumsum_j(I) >= 1
// (hard reset to exactly 0.0 -> exactly periodic spike train, period n).
// n = med3(ceil(rcp(I)), 0, 17); provably equals the fp32-cumsum crossing
// outside the |r - nearest-int| < GUARD band; in-band waves (P ~ 1e-4) are
// patched with the exact 16-step simulation via acc += (A_exact - A_opt)*w2.

typedef float v2f __attribute__((ext_vector_type(2)));

constexpr int TSTEPS = 16;
constexpr int NB = 8;                  // batch rows per block (grid = 2048)
constexpr int NP = NB / 2;
constexpr float GUARD = 4e-5f;
constexpr float GTHR  = 0.5f - GUARD;

// ---- one h-stream: load, classify 8 elems, bpermute A, accumulate ----
#define CLASSIFY_STREAM(sfx, hexpr)                                          \
    const int hh##sfx = (hexpr);                                             \
    const float4 w1##sfx = *reinterpret_cast<const float4*>(W1 + (size_t)hh##sfx * 4); \
    const float  bb##sfx  = b1[hh##sfx];                                     \
    const float  w2a##sfx = W2[hh##sfx];                                     \
    const float  w2b##sfx = W2[H + hh##sfx];                                 \
    v2f I##sfx[NP], Ap##sfx[NP];                                             \
    _Pragma("unroll")                                                        \
    for (int ip = 0; ip < NP; ++ip) {                                        \
        v2f t = __builtin_elementwise_fma(xp3[ip], (v2f){w1##sfx.w, w1##sfx.w}, (v2f){bb##sfx, bb##sfx}); \
        t = __builtin_elementwise_fma(xp2[ip], (v2f){w1##sfx.z, w1##sfx.z}, t); \
        t = __builtin_elementwise_fma(xp1[ip], (v2f){w1##sfx.y, w1##sfx.y}, t); \
        I##sfx[ip] = __builtin_elementwise_fma(xp0[ip], (v2f){w1##sfx.x, w1##sfx.x}, t); \
    }                                                                        \
    _Pragma("unroll")                                                        \
    for (int ip = 0; ip < NP; ++ip) {                                        \
        {   const float r = __builtin_amdgcn_rcpf(I##sfx[ip].x);             \
            const float c = __builtin_ceilf(r);                              \
            const int idx = (int)__builtin_amdgcn_fmed3f(c, 0.0f, 17.0f) << 2; \
            emax = fmaxf(emax, fabsf((r - c) + 0.5f));                       \
            Ap##sfx[ip].x = __int_as_float(__builtin_amdgcn_ds_bpermute(idx, table_reg)); } \
        {   const float r = __builtin_amdgcn_rcpf(I##sfx[ip].y);             \
            const float c = __builtin_ceilf(r);                              \
            const int idx = (int)__builtin_amdgcn_fmed3f(c, 0.0f, 17.0f) << 2; \
            emax = fmaxf(emax, fabsf((r - c) + 0.5f));                       \
            Ap##sfx[ip].y = __int_as_float(__builtin_amdgcn_ds_bpermute(idx, table_reg)); } \
    }                                                                        \
    _Pragma("unroll")                                                        \
    for (int ip = 0; ip < NP; ++ip) {                                        \
        acc##sfx##0[ip] = __builtin_elementwise_fma(Ap##sfx[ip], (v2f){w2a##sfx, w2a##sfx}, acc##sfx##0[ip]); \
        acc##sfx##1[ip] = __builtin_elementwise_fma(Ap##sfx[ip], (v2f){w2b##sfx, w2b##sfx}, acc##sfx##1[ip]); \
    }

// ---- rare exact patch-up for one stream (dA == 0.0 if unaffected) ----
#define CORRECT_STREAM(sfx)                                                  \
    _Pragma("unroll")                                                        \
    for (int ip = 0; ip < NP; ++ip) {                                        \
        _Pragma("unroll")                                                    \
        for (int u = 0; u < 2; ++u) {                                        \
            const float I = u ? I##sfx[ip].y : I##sfx[ip].x;                 \
            float v = 0.0f; int cnt = 0;                                     \
            _Pragma("unroll")                                                \
            for (int t = 0; t < TSTEPS; ++t) { v += I; cnt += (v < 1.0f) ? 1 : 0; } \
            const float An = __int_as_float(                                 \
                __builtin_amdgcn_ds_bpermute((cnt + 1) << 2, table_reg));    \
            const float Ao = u ? Ap##sfx[ip].y : Ap##sfx[ip].x;              \
            const float dA = An - Ao;                                        \
            if (u) { acc##sfx##0[ip].y = fmaf(dA, w2a##sfx, acc##sfx##0[ip].y); \
                     acc##sfx##1[ip].y = fmaf(dA, w2b##sfx, acc##sfx##1[ip].y); } \
            else   { acc##sfx##0[ip].x = fmaf(dA, w2a##sfx, acc##sfx##0[ip].x); \
                     acc##sfx##1[ip].x = fmaf(dA, w2b##sfx, acc##sfx##1[ip].x); } \
        }                                                                    \
    }

template <int CITERS>
__global__ __launch_bounds__(256, 4) void dqsn_fwd(
    const float* __restrict__ x,
    const float* __restrict__ W1,
    const float* __restrict__ b1,
    const float* __restrict__ W2,
    const float* __restrict__ b2,
    float* __restrict__ out,
    int B, int H, int iters_rt)
{
    const int tid  = threadIdx.x;
    const int lane = tid & 63;
    const int b0   = blockIdx.x * NB;

    // per-lane A(n) table: lane l (1..16) holds A for period n=l.
    // lanes 0 and 17+ hold 0.0 (n=0: I<=0; n=17: no spike within 16 steps).
    float tval = 0.0f;
    if (lane >= 1 && lane <= TSTEPS) {
        unsigned mm = 0;
        for (int k = lane; k <= TSTEPS; k += lane) mm |= 1u << (k - 1);
        tval = (float)mm * 0x1p-16f;   // exact: mm < 2^17
    }
    const int table_reg = __float_as_int(tval);

    // x rows packed as (row 2ip, row 2ip+1) pairs for v_pk_fma_f32
    v2f xp0[NP], xp1[NP], xp2[NP], xp3[NP];
#pragma unroll
    for (int ip = 0; ip < NP; ++ip) {
        int ra = b0 + 2 * ip, rb = b0 + 2 * ip + 1;
        ra = (ra < B) ? ra : B - 1;
        rb = (rb < B) ? rb : B - 1;
        xp0[ip] = (v2f){x[ra * 4 + 0], x[rb * 4 + 0]};
        xp1[ip] = (v2f){x[ra * 4 + 1], x[rb * 4 + 1]};
        xp2[ip] = (v2f){x[ra * 4 + 2], x[rb * 4 + 2]};
        xp3[ip] = (v2f){x[ra * 4 + 3], x[rb * 4 + 3]};
    }

    v2f accA0[NP], accA1[NP], accB0[NP], accB1[NP];
#pragma unroll
    for (int ip = 0; ip < NP; ++ip) {
        accA0[ip] = (v2f){0.0f, 0.0f};
        accA1[ip] = (v2f){0.0f, 0.0f};
        accB0[ip] = (v2f){0.0f, 0.0f};
        accB1[ip] = (v2f){0.0f, 0.0f};
    }

    if (CITERS > 0) {
        // compile-time path: two h-streams per iteration, CITERS/2 iters
#pragma unroll
        for (int it = 0; it < CITERS / 2; ++it) {
            float emax = 0.0f;
            CLASSIFY_STREAM(A, tid + (it << 9))
            CLASSIFY_STREAM(B, tid + (it << 9) + 256)

            if (__builtin_expect((unsigned long long)__ballot(emax > GTHR), 0)) {
                CORRECT_STREAM(A)
                CORRECT_STREAM(B)
            }
        }
    } else {
        // runtime path: single stream per iteration
        for (int it = 0; it < iters_rt; ++it) {
            float emax = 0.0f;
            CLASSIFY_STREAM(A, tid + (it << 8))
            if (__builtin_expect((unsigned long long)__ballot(emax > GTHR), 0)) {
                CORRECT_STREAM(A)
            }
        }
    }

    // merge stream accumulators
    v2f acc0[NP], acc1[NP];
#pragma unroll
    for (int ip = 0; ip < NP; ++ip) {
        acc0[ip] = accA0[ip] + accB0[ip];
        acc1[ip] = accA1[ip] + accB1[ip];
    }

    // ---- epilogue: value-halving wave reduction (17 DS per wave) ----
    float v[16];
#pragma unroll
    for (int ip = 0; ip < NP; ++ip) {
        v[4 * ip + 0] = acc0[ip].x;   // row 2ip,   out0
        v[4 * ip + 1] = acc1[ip].x;   // row 2ip,   out1
        v[4 * ip + 2] = acc0[ip].y;   // row 2ip+1, out0
        v[4 * ip + 3] = acc1[ip].y;   // row 2ip+1, out1
    }

    {   // off=32: 16 -> 8 values
        const bool up = (lane & 32) != 0;
#pragma unroll
        for (int k = 0; k < 8; ++k) {
            const float mine = up ? v[k] : v[k + 8];
            const float recv = __shfl_xor(mine, 32, 64);
            v[k] = (up ? v[k + 8] : v[k]) + recv;
        }
    }
    {   // off=16: 8 -> 4
        const bool up = (lane & 16) != 0;
#pragma unroll
        for (int k = 0; k < 4; ++k) {
            const float mine = up ? v[k] : v[k + 4];
            const float recv = __shfl_xor(mine, 16, 64);
            v[k] = (up ? v[k + 4] : v[k]) + recv;
        }
    }
    {   // off=8: 4 -> 2
        const bool up = (lane & 8) != 0;
#pragma unroll
        for (int k = 0; k < 2; ++k) {
            const float mine = up ? v[k] : v[k + 2];
            const float recv = __shfl_xor(mine, 8, 64);
            v[k] = (up ? v[k + 2] : v[k]) + recv;
        }
    }
    {   // off=4: 2 -> 1; value index = (lane>>2)&15
        const bool up = (lane & 4) != 0;
        const float mine = up ? v[0] : v[1];
        const float recv = __shfl_xor(mine, 4, 64);
        v[0] = (up ? v[1] : v[0]) + recv;
    }
    float tot = v[0];
    tot += __shfl_xor(tot, 1, 64);
    tot += __shfl_xor(tot, 2, 64);

    __shared__ float red[4][16];
    if ((lane & 3) == 0) red[tid >> 6][lane >> 2] = tot;
    __syncthreads();

    if (tid < 16) {
        const float s = (red[0][tid] + red[1][tid]) + (red[2][tid] + red[3][tid]);
        const int i = tid >> 1;
        const int o = tid & 1;
        if (b0 + i < B)
            out[(b0 + i) * 2 + o] = s + b2[o] * (1.0f - 0x1p-16f);
    }
}

extern "C" void kernel_launch(void* const* d_in, const int* in_sizes, int n_in,
                              void* d_out, int out_size, void* d_ws, size_t ws_size,
                              hipStream_t stream) {
    const float* x  = (const float*)d_in[0];
    const float* W1 = (const float*)d_in[1];
    const float* b1 = (const float*)d_in[2];
    const float* W2 = (const float*)d_in[3];
    const float* b2 = (const float*)d_in[4];
    float* out = (float*)d_out;

    const int B = in_sizes[0] / 4;   // 16384
    const int H = in_sizes[2];       // 4096

    const int grid = (B + NB - 1) / NB;
    if (H == 4096) {
        dqsn_fwd<16><<<grid, 256, 0, stream>>>(x, W1, b1, W2, b2, out, B, H, 16);
    } else {
        dqsn_fwd<0><<<grid, 256, 0, stream>>>(x, W1, b1, W2, b2, out, B, H, H / 256);
    }
}

// Round 12
// 31.852 us; speedup vs baseline: 1.3905x; 1.3905x over previous
//
#include <hip/hip_runtime.h>

// DQSN forward, fully fused (v9): R3's tight-loop/per-element-guard structure
// (the only shape that sustained ~90% VALUBusy) carrying R10's trimmed math.
//
// out[b,o] = sum_h W2[o,h] * A[b,h] + b2[o] * (1 - 2^-16)
// A depends only on n = first j in 1..16 with fp32-cumsum_j(I) >= 1
// (hard reset to exactly 0.0 -> exactly periodic spike train, period n).
// n = med3(ceil(rcp(I)), 0, 17); provably equals the fp32-cumsum crossing
// outside the |r - nearest-int| < GUARD band (rcp err ~2e-6, cumsum shift
// <= 1.6e-5); in-band elements (P ~ 1e-4) fall back to the exact 16-step
// simulation, keeping decisions bit-faithful to the reference dynamics.
// A(n) via per-lane register table + ds_bpermute (cheaper than arithmetic
// A: R9 falsified the DS-bound hypothesis).

constexpr int TSTEPS = 16;
constexpr int NB = 8;                  // batch rows per block (grid = 2048)
constexpr float GUARD = 4e-5f;
constexpr float GTHR  = 0.5f - GUARD;

__global__ __launch_bounds__(256) void dqsn_fwd(
    const float* __restrict__ x,
    const float* __restrict__ W1,
    const float* __restrict__ b1,
    const float* __restrict__ W2,
    const float* __restrict__ b2,
    float* __restrict__ out,
    int B, int H)
{
    const int tid  = threadIdx.x;
    const int lane = tid & 63;
    const int b0   = blockIdx.x * NB;

    // per-lane A(n) table: lane l (1..16) holds A for period n=l.
    // lanes 0 and 17+ hold 0.0 (n=0: I<=0; n=17: no spike within 16 steps).
    float tval = 0.0f;
    if (lane >= 1 && lane <= TSTEPS) {
        unsigned mm = 0;
        for (int k = lane; k <= TSTEPS; k += lane) mm |= 1u << (k - 1);
        tval = (float)mm * 0x1p-16f;   // exact: mm < 2^17
    }
    const int table_reg = __float_as_int(tval);

    // x rows for this block: block-uniform -> scalar regs
    float xs0[NB], xs1[NB], xs2[NB], xs3[NB];
#pragma unroll
    for (int i = 0; i < NB; ++i) {
        const int bi = (b0 + i < B) ? (b0 + i) : (B - 1);
        xs0[i] = x[bi * 4 + 0];
        xs1[i] = x[bi * 4 + 1];
        xs2[i] = x[bi * 4 + 2];
        xs3[i] = x[bi * 4 + 3];
    }

    float acc0[NB], acc1[NB];
#pragma unroll
    for (int i = 0; i < NB; ++i) { acc0[i] = 0.0f; acc1[i] = 0.0f; }

    // tight runtime loop, minimal live-set (one element in flight)
    for (int h = tid; h < H; h += 256) {
        const float4 w1 = *reinterpret_cast<const float4*>(W1 + (size_t)h * 4);
        const float bb  = b1[h];
        const float w2a = W2[h];
        const float w2b = W2[H + h];

#pragma unroll
        for (int i = 0; i < NB; ++i) {
            const float I = fmaf(xs0[i], w1.x,
                            fmaf(xs1[i], w1.y,
                            fmaf(xs2[i], w1.z,
                            fmaf(xs3[i], w1.w, bb))));

            const float r = __builtin_amdgcn_rcpf(I);
            const float c = __builtin_ceilf(r);
            int idx = (int)__builtin_amdgcn_fmed3f(c, 0.0f, 17.0f) << 2;

            // per-element guard: near a breakpoint -> exact 16-step fallback
            if (__builtin_expect(
                    (unsigned long long)__ballot(fabsf((r - c) + 0.5f) > GTHR), 0)) {
                float v = 0.0f;
                int cnt = 0;
#pragma unroll
                for (int t = 0; t < TSTEPS; ++t) {
                    v += I;
                    cnt += (v < 1.0f) ? 1 : 0;
                }
                idx = (cnt + 1) << 2;          // exact for all lanes
            }

            const float A = __int_as_float(__builtin_amdgcn_ds_bpermute(idx, table_reg));
            acc0[i] = fmaf(A, w2a, acc0[i]);
            acc1[i] = fmaf(A, w2b, acc1[i]);
        }
    }

    // ---- epilogue: value-halving wave reduction (R10's, verified) ----
    // logical index j = 2*row_local + o
    float v[16];
#pragma unroll
    for (int i = 0; i < NB; ++i) {
        v[2 * i + 0] = acc0[i];
        v[2 * i + 1] = acc1[i];
    }

    {   // off=32: 16 -> 8 values
        const bool up = (lane & 32) != 0;
#pragma unroll
        for (int k = 0; k < 8; ++k) {
            const float mine = up ? v[k] : v[k + 8];
            const float recv = __shfl_xor(mine, 32, 64);
            v[k] = (up ? v[k + 8] : v[k]) + recv;
        }
    }
    {   // off=16: 8 -> 4
        const bool up = (lane & 16) != 0;
#pragma unroll
        for (int k = 0; k < 4; ++k) {
            const float mine = up ? v[k] : v[k + 4];
            const float recv = __shfl_xor(mine, 16, 64);
            v[k] = (up ? v[k + 4] : v[k]) + recv;
        }
    }
    {   // off=8: 4 -> 2
        const bool up = (lane & 8) != 0;
#pragma unroll
        for (int k = 0; k < 2; ++k) {
            const float mine = up ? v[k] : v[k + 2];
            const float recv = __shfl_xor(mine, 8, 64);
            v[k] = (up ? v[k + 2] : v[k]) + recv;
        }
    }
    {   // off=4: 2 -> 1; value index = (lane>>2)&15
        const bool up = (lane & 4) != 0;
        const float mine = up ? v[0] : v[1];
        const float recv = __shfl_xor(mine, 4, 64);
        v[0] = (up ? v[1] : v[0]) + recv;
    }
    float tot = v[0];
    tot += __shfl_xor(tot, 1, 64);
    tot += __shfl_xor(tot, 2, 64);

    __shared__ float red[4][16];
    if ((lane & 3) == 0) red[tid >> 6][lane >> 2] = tot;
    __syncthreads();

    if (tid < 16) {
        const float s = (red[0][tid] + red[1][tid]) + (red[2][tid] + red[3][tid]);
        const int i = tid >> 1;
        const int o = tid & 1;
        if (b0 + i < B)
            out[(b0 + i) * 2 + o] = s + b2[o] * (1.0f - 0x1p-16f);
    }
}

extern "C" void kernel_launch(void* const* d_in, const int* in_sizes, int n_in,
                              void* d_out, int out_size, void* d_ws, size_t ws_size,
                              hipStream_t stream) {
    const float* x  = (const float*)d_in[0];
    const float* W1 = (const float*)d_in[1];
    const float* b1 = (const float*)d_in[2];
    const float* W2 = (const float*)d_in[3];
    const float* b2 = (const float*)d_in[4];
    float* out = (float*)d_out;

    const int B = in_sizes[0] / 4;   // 16384
    const int H = in_sizes[2];       // 4096

    const int grid = (B + NB - 1) / NB;
    dqsn_fwd<<<grid, 256, 0, stream>>>(x, W1, b1, W2, b2, out, B, H);
}